// Round 1
// baseline (43606.522 us; speedup 1.0000x reference)
//
#include <hip/hip_runtime.h>
#include <hip/hip_bf16.h>
#include <math.h>

namespace {

constexpr int D    = 768;
constexpr int NH   = 12;
constexpr int PTOT = 257;
constexpr int NB   = 2;
constexpr int TT   = 16;
constexpr int NTOK = NB * TT * PTOT;   // 8224
constexpr int NPAT = NB * TT * 256;    // 8192
constexpr int QKVD = 3 * D;            // 2304

// ---------------- unfold x -> xp (8192 x 768) ----------------
__global__ __launch_bounds__(256) void unfold_kernel(const float* __restrict__ x,
                                                     float* __restrict__ xp) {
  int idx = blockIdx.x * 256 + threadIdx.x;
  if (idx >= NPAT * D) return;
  int f  = idx % D;            // c*256 + i*16 + j
  int pg = idx / D;            // nt*256 + hp*16 + wp
  int c = f >> 8;
  int r = f & 255;
  int i = r >> 4, j = r & 15;
  int nt = pg >> 8;
  int s  = pg & 255;
  int hp = s >> 4, wp = s & 15;
  xp[idx] = x[(size_t)(nt * 3 + c) * 65536 + (size_t)(hp * 16 + i) * 256 + (wp * 16 + j)];
}

// ---------------- transpose patch_w (768x768) -> (feat, d) ----------------
__global__ __launch_bounds__(256) void transpose_pw(const float* __restrict__ pw,
                                                    float* __restrict__ pwT) {
  int idx = blockIdx.x * 256 + threadIdx.x;
  if (idx >= D * D) return;
  int d = idx / D, f = idx % D;
  pwT[(size_t)f * D + d] = pw[idx];
}

// ---------------- assemble h = [cls|tok] + pos + time (+patch_b) ----------------
__global__ __launch_bounds__(256) void assemble_kernel(const float* __restrict__ tok,
    const float* __restrict__ pb, const float* __restrict__ cls,
    const float* __restrict__ pos, const float* __restrict__ tim,
    float* __restrict__ h) {
  int idx = blockIdx.x * 256 + threadIdx.x;
  if (idx >= NTOK * D) return;
  int d = idx % D;
  int tokid = idx / D;
  int p  = tokid % PTOT;
  int nt = tokid / PTOT;
  int t  = nt % TT;
  float v = pos[p * D + d] + tim[t * D + d];
  if (p == 0) v += cls[d];
  else        v += tok[(size_t)(nt * 256 + (p - 1)) * D + d] + pb[d];
  h[idx] = v;
}

// ---------------- generic fp32 tiled GEMM: C = A(MxK)@B(KxN) + bias (+=) ----------------
__global__ __launch_bounds__(256) void gemm_nn(
    const float* __restrict__ A, const float* __restrict__ B,
    const float* __restrict__ bias, float* __restrict__ C,
    int M, int N, int K, int residual)
{
  __shared__ float As[16][64];
  __shared__ float Bs[16][64];
  int tid = threadIdx.x;
  int tx = tid & 15, ty = tid >> 4;
  int bm = blockIdx.y * 64, bn = blockIdx.x * 64;
  float acc[4][4] = {};
  for (int k0 = 0; k0 < K; k0 += 16) {
    // A tile: 64 rows x 16 k, each thread loads float4 along k
    int m  = tid >> 2;
    int kq = (tid & 3) << 2;
    float4 av = make_float4(0.f, 0.f, 0.f, 0.f);
    if (bm + m < M) av = *(const float4*)(A + (size_t)(bm + m) * K + k0 + kq);
    As[kq + 0][m] = av.x; As[kq + 1][m] = av.y; As[kq + 2][m] = av.z; As[kq + 3][m] = av.w;
    // B tile: 16 k x 64 n
    int kk = tid >> 4;
    int nn = (tid & 15) << 2;
    float4 bv = *(const float4*)(B + (size_t)(k0 + kk) * N + bn + nn);
    *(float4*)&Bs[kk][nn] = bv;
    __syncthreads();
    #pragma unroll
    for (int k = 0; k < 16; ++k) {
      float a[4], b[4];
      #pragma unroll
      for (int i = 0; i < 4; ++i) { a[i] = As[k][ty * 4 + i]; b[i] = Bs[k][tx * 4 + i]; }
      #pragma unroll
      for (int i = 0; i < 4; ++i)
        #pragma unroll
        for (int j = 0; j < 4; ++j)
          acc[i][j] = fmaf(a[i], b[j], acc[i][j]);
    }
    __syncthreads();
  }
  #pragma unroll
  for (int i = 0; i < 4; ++i) {
    int row = bm + ty * 4 + i;
    if (row >= M) continue;
    #pragma unroll
    for (int j = 0; j < 4; ++j) {
      int col = bn + tx * 4 + j;
      float v = acc[i][j];
      if (bias) v += bias[col];
      size_t off = (size_t)row * N + col;
      if (residual) C[off] += v; else C[off] = v;
    }
  }
}

// ---------------- spatial attention: one wave per (batch-head, query) ----------------
__global__ __launch_bounds__(256) void attn_spatial(const float* __restrict__ qkv,
                                                    float* __restrict__ o) {
  __shared__ float sc[4][PTOT];
  int lane = threadIdx.x & 63;
  int widx = threadIdx.x >> 6;
  int bh = blockIdx.x;                 // nt*NH + head, 0..383
  int qi = blockIdx.y * 4 + widx;
  if (qi >= PTOT) return;
  int nt = bh / NH, head = bh % NH;
  size_t base = (size_t)nt * PTOT;
  const float* qp = qkv + (base + qi) * QKVD + head * 64;
  float qd = qp[lane];
  float mx = -1e30f;
  for (int j = 0; j < PTOT; ++j) {
    const float* kp = qkv + (base + j) * QKVD + D + head * 64;
    float p = qd * kp[lane];
    #pragma unroll
    for (int off = 32; off; off >>= 1) p += __shfl_down(p, off);
    p = __shfl(p, 0) * 0.125f;
    if (lane == 0) sc[widx][j] = p;
    mx = fmaxf(mx, p);
  }
  float sum = 0.f, acc = 0.f;
  for (int j = 0; j < PTOT; ++j) {
    float e = __expf(sc[widx][j] - mx);
    const float* vp = qkv + (base + j) * QKVD + 2 * D + head * 64;
    acc = fmaf(e, vp[lane], acc);
    sum += e;
  }
  o[(base + qi) * D + head * 64 + lane] = acc / sum;
}

// ---------------- temporal attention: one wave per (n, head, p, query) ----------------
__global__ __launch_bounds__(256) void attn_temporal(const float* __restrict__ qkv,
                                                     float* __restrict__ o) {
  int lane = threadIdx.x & 63;
  int widx = threadIdx.x >> 6;
  int c  = blockIdx.x;                 // (n*NH + head)*PTOT + p, 0..6167
  int qi = blockIdx.y * 4 + widx;      // 0..15
  int p  = c % PTOT;
  int nh = c / PTOT;
  int n  = nh / NH, head = nh % NH;
  const float* qp = qkv + (size_t)((n * TT + qi) * PTOT + p) * QKVD + head * 64;
  float qd = qp[lane];
  float scr[TT];
  float mx = -1e30f;
  #pragma unroll
  for (int j = 0; j < TT; ++j) {
    const float* kp = qkv + (size_t)((n * TT + j) * PTOT + p) * QKVD + D + head * 64;
    float s = qd * kp[lane];
    #pragma unroll
    for (int off = 32; off; off >>= 1) s += __shfl_down(s, off);
    s = __shfl(s, 0) * 0.125f;
    scr[j] = s;
    mx = fmaxf(mx, s);
  }
  float sum = 0.f, acc = 0.f;
  #pragma unroll
  for (int j = 0; j < TT; ++j) {
    float e = __expf(scr[j] - mx);
    const float* vp = qkv + (size_t)((n * TT + j) * PTOT + p) * QKVD + 2 * D + head * 64;
    acc = fmaf(e, vp[lane], acc);
    sum += e;
  }
  o[(size_t)((n * TT + qi) * PTOT + p) * D + head * 64 + lane] = acc / sum;
}

// ---------------- final LN on cls rows + mean over t + head ----------------
__device__ __forceinline__ float block_sum(float v, float* lds) {
  #pragma unroll
  for (int off = 32; off; off >>= 1) v += __shfl_down(v, off);
  __syncthreads();
  if ((threadIdx.x & 63) == 0) lds[threadIdx.x >> 6] = v;
  __syncthreads();
  return lds[0] + lds[1] + lds[2] + lds[3];
}

__global__ __launch_bounds__(256) void head_kernel(const float* __restrict__ h,
    const float* __restrict__ g, const float* __restrict__ b,
    const float* __restrict__ hw, const float* __restrict__ hb,
    float* __restrict__ out) {
  __shared__ float lds[4];
  int n = blockIdx.x, tid = threadIdx.x;
  float logit = 0.f;
  for (int t = 0; t < TT; ++t) {
    const float* row = h + (size_t)((n * TT + t) * PTOT) * D;   // cls token (p=0)
    float v[3]; float s = 0.f;
    #pragma unroll
    for (int i = 0; i < 3; ++i) { v[i] = row[tid + 256 * i]; s += v[i]; }
    s = block_sum(s, lds);
    float mu = s * (1.f / D);
    float s2 = 0.f;
    #pragma unroll
    for (int i = 0; i < 3; ++i) { float d0 = v[i] - mu; s2 += d0 * d0; }
    s2 = block_sum(s2, lds);
    float rstd = rsqrtf(s2 * (1.f / D) + 1e-5f);
    float dot = 0.f;
    #pragma unroll
    for (int i = 0; i < 3; ++i) {
      int d0 = tid + 256 * i;
      float y = (v[i] - mu) * rstd * g[d0] + b[d0];
      dot += y * hw[d0];
    }
    dot = block_sum(dot, lds);
    logit += dot;
  }
  if (tid == 0) out[n] = logit * (1.f / TT) + hb[0];
}

} // namespace

extern "C" void kernel_launch(void* const* d_in, const int* in_sizes, int n_in,
                              void* d_out, int out_size, void* d_ws, size_t ws_size,
                              hipStream_t stream) {
  const float* x       = (const float*)d_in[0];
  const float* patch_w = (const float*)d_in[1];
  const float* patch_b = (const float*)d_in[2];
  const float* cls     = (const float*)d_in[3];
  const float* pos     = (const float*)d_in[4];
  const float* tim     = (const float*)d_in[5];
  const float* wqkv_s  = (const float*)d_in[6];
  const float* bqkv_s  = (const float*)d_in[7];
  const float* wqkv_t  = (const float*)d_in[8];
  const float* bqkv_t  = (const float*)d_in[9];
  const float* wproj   = (const float*)d_in[10];
  const float* bproj   = (const float*)d_in[11];
  const float* ln_g    = (const float*)d_in[12];
  const float* ln_b    = (const float*)d_in[13];
  const float* head_w  = (const float*)d_in[14];
  const float* head_b  = (const float*)d_in[15];
  float* out = (float*)d_out;

  // workspace layout (fp32): h | qkv | o   (xp & pwT alias qkv pre-layers; tok aliases o)
  float* h   = (float*)d_ws;
  float* qkv = h   + (size_t)NTOK * D;       //  6,316,032 floats
  float* o   = qkv + (size_t)NTOK * QKVD;    // 18,948,096 floats
  float* xp  = qkv;                          // alias: used only before layer loop
  float* pwT = qkv + (size_t)NPAT * D;       // alias
  float* tok = o;                            // alias

  // ---- patch embed ----
  unfold_kernel<<<(NPAT * D + 255) / 256, 256, 0, stream>>>(x, xp);
  transpose_pw<<<(D * D + 255) / 256, 256, 0, stream>>>(patch_w, pwT);
  gemm_nn<<<dim3(D / 64, (NPAT + 63) / 64), 256, 0, stream>>>(
      xp, pwT, nullptr, tok, NPAT, D, D, 0);
  assemble_kernel<<<(NTOK * D + 255) / 256, 256, 0, stream>>>(tok, patch_b, cls, pos, tim, h);

  // ---- transformer layers ----
  for (int l = 0; l < 12; ++l) {
    gemm_nn<<<dim3(QKVD / 64, (NTOK + 63) / 64), 256, 0, stream>>>(
        h, wqkv_s + (size_t)l * D * QKVD, bqkv_s + (size_t)l * QKVD, qkv, NTOK, QKVD, D, 0);
    attn_spatial<<<dim3(NB * TT * NH, (PTOT + 3) / 4), 256, 0, stream>>>(qkv, o);
    gemm_nn<<<dim3(D / 64, (NTOK + 63) / 64), 256, 0, stream>>>(
        o, wproj + (size_t)l * D * D, bproj + (size_t)l * D, h, NTOK, D, D, 1);

    gemm_nn<<<dim3(QKVD / 64, (NTOK + 63) / 64), 256, 0, stream>>>(
        h, wqkv_t + (size_t)l * D * QKVD, bqkv_t + (size_t)l * QKVD, qkv, NTOK, QKVD, D, 0);
    attn_temporal<<<dim3(NB * NH * PTOT, 4), 256, 0, stream>>>(qkv, o);
    gemm_nn<<<dim3(D / 64, (NTOK + 63) / 64), 256, 0, stream>>>(
        o, wproj + (size_t)l * D * D, bproj + (size_t)l * D, h, NTOK, D, D, 1);
  }

  // ---- final LN (cls rows only) + temporal mean + head ----
  head_kernel<<<2, 256, 0, stream>>>(h, ln_g, ln_b, head_w, head_b, out);
}